// Round 25
// baseline (471.174 us; speedup 1.0000x reference)
//
#include <hip/hip_runtime.h>

using bf16   = __bf16;
using bf16x4 = __bf16 __attribute__((ext_vector_type(4)));
using bf16x8 = __bf16 __attribute__((ext_vector_type(8)));
using f32x4  = float __attribute__((ext_vector_type(4)));

#define MFMA_BF16(a, b, c) __builtin_amdgcn_mfma_f32_16x16x32_bf16((a), (b), (c), 0, 0, 0)

constexpr int BATCH = 64, SEQ = 257, DIM = 768, NH = 12;
constexpr size_t WE = (size_t)DIM * DIM;

__device__ inline void gload_lds16(const bf16* g, bf16* l) {
  __builtin_amdgcn_global_load_lds(
      (const __attribute__((address_space(1))) void*)g,
      (__attribute__((address_space(3))) void*)l, 16, 0, 0);
}

// ---------------- weights fp32 -> bf16, order [Wq | Wk*c1 | Wv*c1 | Wk | Wv | Wo] ----------------
__global__ __launch_bounds__(256) void cvt_weights6(
    const float* __restrict__ wq, const float* __restrict__ wk,
    const float* __restrict__ wv, const float* __restrict__ wo,
    const float* __restrict__ c1, bf16* __restrict__ dst) {
  const size_t i = (size_t)blockIdx.x * 256 + threadIdx.x;  // float4 index
  const size_t per = WE / 4;
  if (i >= 6 * per) return;
  const int region = (int)(i / per);
  const size_t within = i % per;
  const float* srcs[6] = {wq, wk, wv, wk, wv, wo};
  const float4 f = ((const float4*)srcs[region])[within];
  float v[4] = {f.x, f.y, f.z, f.w};
  if (region == 1 || region == 2) {
    const int c0 = (int)((within * 4) % DIM);
#pragma unroll
    for (int j = 0; j < 4; ++j) v[j] *= c1[c0 + j];
  }
  bf16* o = dst + i * 4;
#pragma unroll
  for (int j = 0; j < 4; ++j) o[j] = (bf16)v[j];
}

// ---------------- hs fp32 -> bf16 ----------------
__global__ __launch_bounds__(256) void cvt_hs(const float* __restrict__ src,
                                              bf16* __restrict__ dst, int n4) {
  const int i = blockIdx.x * 256 + threadIdx.x;
  if (i >= n4) return;
  const float4 f = ((const float4*)src)[i];
  bf16* o = dst + (size_t)i * 4;
  o[0] = (bf16)f.x; o[1] = (bf16)f.y; o[2] = (bf16)f.z; o[3] = (bf16)f.w;
}

// ---------------- depthwise conv + cls concat -> xb bf16 [B][L][768] ----------------
template <int KS>
__global__ __launch_bounds__(256) void conv_kernel(
    const float* __restrict__ hs, const float* __restrict__ cw, bf16* __restrict__ xb) {
  constexpr int OW = 17 - KS;
  constexpr int NOUT = OW * OW;
  constexpr int L = NOUT + 1;
  constexpr int KSQ = KS * KS;
  constexpr int NP = (NOUT + 7) / 8;
  __shared__ float hsl[256][36];
  __shared__ float wsm[32][KSQ];

  const int t = threadIdx.x;
  const int b = blockIdx.y;
  const int c0 = blockIdx.x * 32;

  const float* src = hs + ((size_t)b * SEQ + 1 + t) * DIM + c0;
#pragma unroll
  for (int j = 0; j < 8; ++j) *(float4*)&hsl[t][4 * j] = ((const float4*)src)[j];

  if (t < 32) {
#pragma unroll
    for (int q = 0; q < KSQ; ++q) wsm[t][q] = cw[(size_t)(c0 + t) * KSQ + q];
    const float cv = hs[(size_t)b * SEQ * DIM + c0 + t];
    xb[(size_t)b * L * DIM + c0 + t] = (bf16)cv;
  }
  __syncthreads();

  const int c = t & 31, pg = t >> 5;
#pragma unroll
  for (int i = 0; i < NP; ++i) {
    const int p = pg * NP + i;
    if (p < NOUT) {
      const int oi = p / OW, oj = p - oi * OW;
      float a = 0.f;
#pragma unroll
      for (int di = 0; di < KS; ++di)
#pragma unroll
        for (int dj = 0; dj < KS; ++dj)
          a += hsl[(oi + di) * 16 + oj + dj][c] * wsm[c][di * KS + dj];
      xb[((size_t)b * L + 1 + p) * DIM + c0 + c] = (bf16)a;
    }
  }
}

// ---------------- GEMM core: 128x256 tile, 512 threads (8 waves = 2x4 of 64x64) ----------------
// 3 LDS buffers (72 KB, 2 blocks/CU), counted vmcnt(3), both-sides chunk swizzle,
// STAGE hoisted to iteration top (r24). No setprio here: m190 measured it NEGATIVE on
// lockstep barrier-synced GEMMs.
// OUT: 1 = KV (N=1536: tN<3 K, >=3 V); 3 = fp32 [M][768]; 4 = QKV (N=2304: Q/K/V per 3).
template <int OUT>
__device__ __forceinline__ void gemm_core(
    bf16* sm, const bf16* A, const bf16* W,
    const float* b0, const float* b1, const float* b2,
    void* Y0, void* Y1, void* Y2, int M, int L, int Lv, int tM, int tN, int tid) {
  constexpr int A_E = 128 * 32;  // 4096 elems / buffer
  constexpr int B_E = 256 * 32;  // 8192 elems / buffer
  bf16* smA = sm;                // 3 buffers A
  bf16* smB = sm + 3 * A_E;      // 3 buffers B

  const int lane = tid & 63;
  const int w = tid >> 6;            // 0..7
  const int wrow = (w >> 2) * 64;    // 0,64
  const int wcol = (w & 3) * 64;     // 0,64,128,192
  const int rl = lane & 15;
  const int g = lane >> 4;
  const int kqs = ((g ^ ((rl >> 1) & 3)) << 3);  // read-side chunk deswizzle

  const int sr = lane >> 2;
  const int sk = (((lane & 3) ^ ((sr >> 1) & 3)) << 3);  // staging global pre-swizzle
  long gar = (long)tM * 128 + w * 16 + sr; if (gar >= M) gar = M - 1;
  const bf16* pa  = A + gar * DIM + sk;
  const bf16* pb0 = W + ((size_t)tN * 256 + (2 * w) * 16 + sr) * DIM + sk;
  const bf16* pb1 = W + ((size_t)tN * 256 + (2 * w + 1) * 16 + sr) * DIM + sk;
  const int la  = w * 512;
  const int lb0 = (2 * w) * 512;
  const int lb1 = (2 * w + 1) * 512;

  const f32x4 zero4 = {0.f, 0.f, 0.f, 0.f};
  f32x4 acc[4][4];
#pragma unroll
  for (int m = 0; m < 4; ++m)
#pragma unroll
    for (int n = 0; n < 4; ++n) acc[m][n] = zero4;

  constexpr int NT = DIM / 32;  // 24 K-steps

#define STAGE(kt_, buf_)                                      \
  do {                                                        \
    const int kb_ = (kt_) * 32;                               \
    gload_lds16(pa  + kb_, smA + (buf_) * A_E + la);          \
    gload_lds16(pb0 + kb_, smB + (buf_) * B_E + lb0);         \
    gload_lds16(pb1 + kb_, smB + (buf_) * B_E + lb1);         \
  } while (0)

  STAGE(0, 0);
  STAGE(1, 1);
  asm volatile("s_waitcnt vmcnt(3)" ::: "memory");
  __builtin_amdgcn_s_barrier();
  __builtin_amdgcn_sched_barrier(0);

  int buf = 0;
  for (int kt = 0; kt < NT; ++kt) {
    if (kt + 2 < NT) {
      const int nb = buf + 2 >= 3 ? buf - 1 : buf + 2;
      STAGE(kt + 2, nb);
    }

    const bf16* Ac = smA + buf * A_E;
    const bf16* Bc = smB + buf * B_E;
    bf16x8 af[4], bfr[4];
#pragma unroll
    for (int m = 0; m < 4; ++m) af[m] = *(const bf16x8*)&Ac[(wrow + m * 16 + rl) * 32 + kqs];
#pragma unroll
    for (int n = 0; n < 4; ++n) bfr[n] = *(const bf16x8*)&Bc[(wcol + n * 16 + rl) * 32 + kqs];
#pragma unroll
    for (int m = 0; m < 4; ++m)
#pragma unroll
      for (int n = 0; n < 4; ++n) acc[m][n] = MFMA_BF16(af[m], bfr[n], acc[m][n]);

    if (kt + 1 < NT) {
      if (kt + 2 < NT) asm volatile("s_waitcnt vmcnt(3)" ::: "memory");
      else             asm volatile("s_waitcnt vmcnt(0)" ::: "memory");
      __builtin_amdgcn_s_barrier();
      __builtin_amdgcn_sched_barrier(0);
    }
    buf = buf == 2 ? 0 : buf + 1;
  }
#undef STAGE

  // ---------------- epilogue ----------------
  if constexpr (OUT == 3) {
#pragma unroll
    for (int n = 0; n < 4; ++n) {
      const int gcol = tN * 256 + wcol + n * 16 + rl;
      const float bia = b0[gcol];
#pragma unroll
      for (int m = 0; m < 4; ++m) {
#pragma unroll
        for (int i = 0; i < 4; ++i) {
          const long grow = (long)tM * 128 + wrow + m * 16 + g * 4 + i;
          if (grow < M) ((float*)Y0)[grow * DIM + gcol] = acc[m][n][i] + bia;
        }
      }
    }
    return;
  }

  bf16* smT = sm;
  __syncthreads();  // all compute + DMA done; sm reusable

  const bool qpath = (OUT == 4) && (tN < 3);
  const bool vpath = (OUT == 4) ? (tN >= 6) : (tN >= 3);

  if (vpath) {
    constexpr int TPV = 136;  // row stride pad (col-major store)
    const int cbase = (OUT == 4) ? 1536 : 768;
    const float* bv_ = (OUT == 4) ? b2 : b1;
#pragma unroll
    for (int n = 0; n < 4; ++n) {
      const int col = wcol + n * 16 + rl;
      const float bia = bv_[tN * 256 + col - cbase];
#pragma unroll
      for (int m = 0; m < 4; ++m) {
        const int row = wrow + m * 16 + g * 4;
        bf16x4 v4;
#pragma unroll
        for (int i = 0; i < 4; ++i) v4[i] = (bf16)(acc[m][n][i] + bia);
        *(bf16x4*)(smT + col * TPV + row) = v4;
      }
    }
    __syncthreads();
    bf16* vout = (bf16*)((OUT == 4) ? Y2 : Y1);
    const int tNv = tN - ((OUT == 4) ? 6 : 3);
#pragma unroll
    for (int it = 0; it < 8; ++it) {
      const int c = it * 512 + tid;     // 4096 chunks: 256 cols x 16 row-chunks
      const int coll = c >> 4;
      const int rw0 = (c & 15) * 8;
      const long g2 = (long)tM * 128 + rw0;
      if (g2 < M) {
        const int b2i = (int)(g2 / L);
        const int l2 = (int)(g2 - (long)b2i * L);
        const int cv = tNv * 256 + coll;
        bf16* dst = vout + (((size_t)b2i * NH + (cv >> 6)) * 64 + (cv & 63)) * Lv;
        const bf16x8 v = *(const bf16x8*)(smT + coll * TPV + rw0);
        if (l2 + 8 <= L) {
          *(bf16x8*)(dst + l2) = v;
        } else {
#pragma unroll
          for (int j = 0; j < 8; ++j) {
            const long g3 = g2 + j;
            const int b3 = (int)(g3 / L), l3 = (int)(g3 - (long)b3 * L);
            vout[(((size_t)b3 * NH + (cv >> 6)) * 64 + (cv & 63)) * Lv + l3] = v[j];
          }
        }
      }
    }
  } else {
    constexpr int TPK = 264;  // col stride pad (row-major store)
    const float scale = qpath ? 0.125f : 1.f;
#pragma unroll
    for (int n = 0; n < 4; ++n) {
      const int col = wcol + n * 16 + rl;
      const int gcol = tN * 256 + col;
      float bia;
      if constexpr (OUT == 4) bia = qpath ? b0[gcol] : b1[gcol - 768];
      else                    bia = b0[gcol];
#pragma unroll
      for (int m = 0; m < 4; ++m) {
#pragma unroll
        for (int i = 0; i < 4; ++i) {
          const int row = wrow + m * 16 + g * 4 + i;
          smT[row * TPK + col] = (bf16)((acc[m][n][i] + bia) * scale);
        }
      }
    }
    __syncthreads();
    bf16* kout = (bf16*)(qpath ? Y0 : ((OUT == 4) ? Y1 : Y0));
    const int coff = (OUT == 4 && !qpath) ? 768 : 0;
    const bool kswz = !qpath;  // K outputs chunk-swizzled for attn's linear DMA
#pragma unroll
    for (int it = 0; it < 8; ++it) {
      const int c = it * 512 + tid;     // 4096 chunks: 128 rows x 32 col-chunks
      const int row = c >> 5;
      const int col0 = (c & 31) * 8;
      const long g2 = (long)tM * 128 + row;
      if (g2 < M) {
        const int b2i = (int)(g2 / L);
        const int l2 = (int)(g2 - (long)b2i * L);
        const int gc = tN * 256 + col0 - coff;
        const bf16x8 v = *(const bf16x8*)(smT + row * TPK + col0);
        if (qpath) {
          *(bf16x8*)(kout + (((size_t)b2i * NH + (gc >> 6)) * 257 + l2) * 64 + (gc & 63)) = v;
        } else {
          int dchunk = (gc & 63) >> 3;
          if (kswz) dchunk ^= (l2 & 7);
          *(bf16x8*)(kout + (((size_t)b2i * NH + (gc >> 6)) * L + l2) * 64 + dchunk * 8) = v;
        }
      }
    }
  }
}

__device__ __forceinline__ int m204_swz(int orig, int nwg) {
  const int nq = nwg >> 3, rr = nwg & 7, xcd = orig & 7, base = orig >> 3;
  return (xcd < rr ? xcd * (nq + 1) : rr * (nq + 1) + (xcd - rr) * nq) + base;
}

// ---- QKV0 mega-GEMM: A=hs_bf16, W=[Wq|Wk*c1|Wv*c1], N=2304, nN=9 ----
__global__ __launch_bounds__(512, 4) void gemm_qkv0_kernel(
    const bf16* __restrict__ A, const bf16* __restrict__ W,
    const float* __restrict__ bq, const float* __restrict__ bk, const float* __restrict__ bv,
    bf16* __restrict__ qb, bf16* __restrict__ kb, bf16* __restrict__ vb) {
  __shared__ alignas(16) bf16 sm[36864];
  const int wgid = m204_swz(blockIdx.x, gridDim.x);
  const int tM = wgid / 9, tN = wgid - tM * 9;
  gemm_core<4>(sm, A, W, bq, bk, bv, qb, kb, vb, BATCH * SEQ, 257, 264, tM, tN, threadIdx.x);
}

// ---- fused KV1+KV2 GEMM: [0,594) branch1 (99x6), [594,1032) branch2 (73x6) ----
__global__ __launch_bounds__(512, 4) void gemm_kv12_kernel(
    const bf16* __restrict__ A1, const bf16* __restrict__ A2, const bf16* __restrict__ W,
    const float* __restrict__ bk, const float* __restrict__ bv,
    bf16* __restrict__ k1, bf16* __restrict__ v1,
    bf16* __restrict__ k2, bf16* __restrict__ v2) {
  __shared__ alignas(16) bf16 sm[36864];
  const int wgid = m204_swz(blockIdx.x, gridDim.x);
  if (wgid < 594) {
    const int tM = wgid / 6, tN = wgid - tM * 6;
    gemm_core<1>(sm, A1, W, bk, bv, nullptr, k1, v1, nullptr, BATCH * 197, 197, 200, tM, tN, threadIdx.x);
  } else {
    const int l = wgid - 594;
    const int tM = l / 6, tN = l - tM * 6;
    gemm_core<1>(sm, A2, W, bk, bv, nullptr, k2, v2, nullptr, BATCH * 145, 145, 152, tM, tN, threadIdx.x);
  }
}

// ---- O projection: N=768, nN=3 ----
__global__ __launch_bounds__(512, 4) void gemm_o_kernel(
    const bf16* __restrict__ A, const bf16* __restrict__ W,
    const float* __restrict__ bo, float* __restrict__ out) {
  __shared__ alignas(16) bf16 sm[36864];
  const int wgid = m204_swz(blockIdx.x, gridDim.x);
  const int tM = wgid / 3, tN = wgid - tM * 3;
  gemm_core<3>(sm, A, W, bo, nullptr, nullptr, out, nullptr, nullptr, BATCH * SEQ, 257, 1, tM, tN, threadIdx.x);
}

// ---- cls fixup: branch-0 K/V row l=0 must use UNSCALED Wk/Wv ----
__global__ __launch_bounds__(256) void cls_fixup_kernel(
    const bf16* __restrict__ hsb, const bf16* __restrict__ wk, const bf16* __restrict__ wv,
    const float* __restrict__ bk, const float* __restrict__ bv,
    bf16* __restrict__ k12, bf16* __restrict__ v12) {
  __shared__ float hrow[DIM];
  const int b = blockIdx.y, tile = blockIdx.x, t = threadIdx.x;
  for (int i = t; i < DIM; i += 256) hrow[i] = (float)hsb[(size_t)b * SEQ * DIM + i];
  __syncthreads();
  const bool isv = tile >= 6;
  const int o = (tile - (isv ? 6 : 0)) * 128 + (t >> 1);
  const int half = t & 1;
  const bf16* wrow = (isv ? wv : wk) + (size_t)o * DIM + half * 384;
  float s = 0.f;
#pragma unroll 4
  for (int k = 0; k < 48; ++k) {
    const bf16x8 wv8 = *(const bf16x8*)(wrow + k * 8);
#pragma unroll
    for (int j = 0; j < 8; ++j) s += hrow[half * 384 + k * 8 + j] * (float)wv8[j];
  }
  s += __shfl_xor(s, 1);
  if (!half) {
    s += (isv ? bv : bk)[o];
    if (!isv) {
      k12[(((size_t)b * NH + (o >> 6)) * 257) * 64 + (o & 63)] = (bf16)s;  // l=0: swizzle identity
    } else {
      v12[(((size_t)b * NH + (o >> 6)) * 64 + (o & 63)) * 264] = (bf16)s;
    }
  }
}

// ---------------- fused attention: one block per (b,h), loops over 5 q-tiles ----------------
// (r21/r23-measured structure) + T5 s_setprio around MFMA clusters: blocks here are fully
// independent (no hot-loop barriers) -> the m191 regime where setprio measured +4-7%.
template <int L, int BRANCH>
__global__ __launch_bounds__(256, 2) void attn_kernel(
    const bf16* __restrict__ qb, const bf16* __restrict__ kb, const bf16* __restrict__ vb,
    float* __restrict__ ctx, bf16* __restrict__ xbuf, int Lv) {
  constexpr int LK16 = (L + 15) & ~15;
  constexpr int NKT = LK16 / 16;
  constexpr int LP32 = (L + 31) & ~31;
  constexpr int NK32 = LP32 / 32;
  constexpr int PSTR = LP32 + 8;
  __shared__ alignas(16) bf16 Ks[LK16 * 64];
  __shared__ alignas(16) bf16 Ps[64 * PSTR];

  const int tid = threadIdx.x, lane = tid & 63, w = tid >> 6;
  const int orig = blockIdx.x;
  const int nper = gridDim.x >> 3;
  const int bh = (orig & 7) * nper + (orig >> 3);
  const int b = bh / NH, h = bh % NH;
  const int cl = lane & 15, g = lane >> 4;

  const bf16* kbase = kb + (size_t)bh * L * 64;
  for (int c = tid; c < LK16 * 8; c += 256)
    gload_lds16(kbase + (size_t)c * 8, Ks + (size_t)c * 8);
  __syncthreads();

  const bf16* vbase = vb + (size_t)bh * 64 * Lv;

  for (int qt = 0; qt < 5; ++qt) {
    int sq = qt * 64 + w * 16 + cl;
    if (sq > 256) sq = 256;
    const bf16* qrow = qb + ((size_t)bh * 257 + sq) * 64 + g * 8;
    const bf16x8 aq0 = *(const bf16x8*)qrow;
    const bf16x8 aq1 = *(const bf16x8*)(qrow + 32);

    float sums[4] = {0.f, 0.f, 0.f, 0.f};
    const int prow0 = (w * 16 + g * 4) * PSTR + cl;
#pragma unroll
    for (int kt = 0; kt < NKT; ++kt) {
      const int key0 = kt * 16 + cl;
      const int sw = key0 & 7;
      const char* krow = (const char*)Ks + key0 * 128;
      const bf16x8 bk0 = *(const bf16x8*)(krow + ((g ^ sw) << 4));
      const bf16x8 bk1 = *(const bf16x8*)(krow + (((4 + g) ^ sw) << 4));
      __builtin_amdgcn_s_setprio(1);
      f32x4 z = {0.f, 0.f, 0.f, 0.f};
      z = MFMA_BF16(aq0, bk0, z);
      z = MFMA_BF16(aq1, bk1, z);
      __builtin_amdgcn_s_setprio(0);
      const bool valid = key0 < L;
#pragma unroll
      for (int j = 0; j < 4; ++j) {
        const float p = valid ? __expf(z[j]) : 0.f;
        sums[j] += p;
        Ps[prow0 + j * PSTR + kt * 16] = (bf16)p;
      }
    }
    if constexpr (LP32 > LK16) {
#pragma unroll
      for (int j = 0; j < 4; ++j) Ps[prow0 + j * PSTR + LK16] = (bf16)0.f;
    }

    bf16x8 vr0[4], vr1[4];
#pragma unroll
    for (int nt = 0; nt < 4; ++nt)
      vr0[nt] = *(const bf16x8*)(vbase + (size_t)(nt * 16 + cl) * Lv + g * 8);

#pragma unroll
    for (int j = 0; j < 4; ++j) {
      sums[j] += __shfl_xor(sums[j], 1);
      sums[j] += __shfl_xor(sums[j], 2);
      sums[j] += __shfl_xor(sums[j], 4);
      sums[j] += __shfl_xor(sums[j], 8);
    }
    float inv[4];
#pragma unroll
    for (int j = 0; j < 4; ++j) inv[j] = 1.f / sums[j];

    f32x4 cacc[4];
#pragma unroll
    for (int nt = 0; nt < 4; ++nt) cacc[nt] = f32x4{0.f, 0.f, 0.f, 0.f};
#pragma unroll
    for (int kt = 0; kt < NK32; ++kt) {
      const bool even = (kt & 1) == 0;
      if (kt + 1 < NK32) {
        int kk = (kt + 1) * 32 + g * 8;
        if (kk > Lv - 8) kk = Lv - 8;
#pragma unroll
        for (int nt = 0; nt < 4; ++nt) {
          const bf16x8 v = *(const bf16x8*)(vbase + (size_t)(nt * 16 + cl) * Lv + kk);
          if (even) vr1[nt] = v; else vr0[nt] = v;
        }
      }
      const bf16x8 ap = *(const bf16x8*)&Ps[(w * 16 + cl) * PSTR + kt * 32 + g * 8];
      __builtin_amdgcn_s_setprio(1);
#pragma unroll
      for (int nt = 0; nt < 4; ++nt)
        cacc[nt] = MFMA_BF16(ap, even ? vr0[nt] : vr1[nt], cacc[nt]);
      __builtin_amdgcn_s_setprio(0);
    }

#pragma unroll
    for (int nt = 0; nt < 4; ++nt) {
#pragma unroll
      for (int i = 0; i < 4; ++i) {
        const int s_q = qt * 64 + w * 16 + g * 4 + i;
        if (s_q < 257) {
          const size_t idx = ((size_t)b * 257 + s_q) * DIM + h * 64 + nt * 16 + cl;
          const float val = cacc[nt][i] * inv[i];
          if constexpr (BRANCH == 0)
            ctx[idx] = val;
          else if constexpr (BRANCH == 1)
            ctx[idx] += val;
          else
            xbuf[idx] = (bf16)((ctx[idx] + val) * (1.f / 3.f));
        }
      }
    }
  }
}

extern "C" void kernel_launch(void* const* d_in, const int* in_sizes, int n_in,
                              void* d_out, int out_size, void* d_ws, size_t ws_size,
                              hipStream_t stream) {
  (void)in_sizes; (void)n_in; (void)out_size; (void)ws_size;
  const float* hs = (const float*)d_in[0];
  const float* Wq = (const float*)d_in[1];
  const float* bq = (const float*)d_in[2];
  const float* Wk = (const float*)d_in[3];
  const float* bk = (const float*)d_in[4];
  const float* Wv = (const float*)d_in[5];
  const float* bv = (const float*)d_in[6];
  const float* Wo = (const float*)d_in[7];
  const float* bo = (const float*)d_in[8];
  const float* c1 = (const float*)d_in[9];
  const float* c2 = (const float*)d_in[10];
  const float* c3 = (const float*)d_in[11];
  float* out = (float*)d_out;

  constexpr size_t QB = (size_t)BATCH * NH * SEQ * 64;
  constexpr size_t XB = (size_t)BATCH * SEQ * DIM;
  constexpr size_t K12 = (size_t)BATCH * NH * 257 * 64;
  constexpr size_t V12 = (size_t)BATCH * NH * 64 * 264;
  constexpr size_t XB3 = (size_t)BATCH * 145 * DIM;
  constexpr size_t K3 = (size_t)BATCH * NH * 145 * 64;

  bf16* wbf = (bf16*)d_ws;           // [Wq|Wk*c1|Wv*c1|Wk|Wv|Wo] 6*WE
  bf16* qb  = wbf + 6 * WE;
  bf16* xb  = qb + QB;               // hsb, later conv2 output; finally ctx/3 bf16
  bf16* k12 = xb + XB;               // branch0 K, later branch1 K
  bf16* v12 = k12 + K12;             // branch0 V, later branch1 V
  bf16* xb3 = v12 + V12;             // conv3 output
  bf16* k3  = xb3 + XB3;
  bf16* v3  = k3 + K3;
  bf16* hsb = xb;

  cvt_weights6<<<dim3((unsigned)((6 * WE / 4 + 255) / 256)), 256, 0, stream>>>(Wq, Wk, Wv, Wo, c1, wbf);
  cvt_hs<<<dim3((BATCH * SEQ * DIM / 4 + 255) / 256), 256, 0, stream>>>(hs, hsb, BATCH * SEQ * DIM / 4);

  // ---- branch 0 (1x1 conv folded into weights): Q, K0, V0 in one GEMM + cls fixup ----
  gemm_qkv0_kernel<<<dim3(129 * 9), 512, 0, stream>>>(hsb, wbf, bq, bk, bv, qb, k12, v12);
  cls_fixup_kernel<<<dim3(12, 64), 256, 0, stream>>>(hsb, wbf + 3 * WE, wbf + 4 * WE, bk, bv, k12, v12);
  attn_kernel<257, 0><<<dim3(768), 256, 0, stream>>>(qb, k12, v12, out, xb, 264);

  // ---- branches 1 & 2: convs, fused KV GEMM, attns ----
  conv_kernel<3><<<dim3(24, 64), 256, 0, stream>>>(hs, c2, xb);
  conv_kernel<5><<<dim3(24, 64), 256, 0, stream>>>(hs, c3, xb3);
  gemm_kv12_kernel<<<dim3(594 + 438), 512, 0, stream>>>(xb, xb3, wbf + 3 * WE, bk, bv,
                                                        k12, v12, k3, v3);
  attn_kernel<197, 1><<<dim3(768), 256, 0, stream>>>(qb, k12, v12, out, xb, 200);
  attn_kernel<145, 2><<<dim3(768), 256, 0, stream>>>(qb, k3, v3, out, xb, 152);

  // ---- output projection ----
  gemm_o_kernel<<<dim3(129 * 3), 512, 0, stream>>>(xb, wbf + 5 * WE, bo, out);
}

// Round 26
// 462.912 us; speedup vs baseline: 1.0178x; 1.0178x over previous
//
#include <hip/hip_runtime.h>

using bf16   = __bf16;
using bf16x4 = __bf16 __attribute__((ext_vector_type(4)));
using bf16x8 = __bf16 __attribute__((ext_vector_type(8)));
using f32x4  = float __attribute__((ext_vector_type(4)));

#define MFMA_BF16(a, b, c) __builtin_amdgcn_mfma_f32_16x16x32_bf16((a), (b), (c), 0, 0, 0)

constexpr int BATCH = 64, SEQ = 257, DIM = 768, NH = 12;
constexpr size_t WE = (size_t)DIM * DIM;

__device__ inline void gload_lds16(const bf16* g, bf16* l) {
  __builtin_amdgcn_global_load_lds(
      (const __attribute__((address_space(1))) void*)g,
      (__attribute__((address_space(3))) void*)l, 16, 0, 0);
}

// ---------------- weights fp32 -> bf16, order [Wq | Wk*c1 | Wv*c1 | Wk | Wv | Wo] ----------------
__global__ __launch_bounds__(256) void cvt_weights6(
    const float* __restrict__ wq, const float* __restrict__ wk,
    const float* __restrict__ wv, const float* __restrict__ wo,
    const float* __restrict__ c1, bf16* __restrict__ dst) {
  const size_t i = (size_t)blockIdx.x * 256 + threadIdx.x;  // float4 index
  const size_t per = WE / 4;
  if (i >= 6 * per) return;
  const int region = (int)(i / per);
  const size_t within = i % per;
  const float* srcs[6] = {wq, wk, wv, wk, wv, wo};
  const float4 f = ((const float4*)srcs[region])[within];
  float v[4] = {f.x, f.y, f.z, f.w};
  if (region == 1 || region == 2) {
    const int c0 = (int)((within * 4) % DIM);
#pragma unroll
    for (int j = 0; j < 4; ++j) v[j] *= c1[c0 + j];
  }
  bf16* o = dst + i * 4;
#pragma unroll
  for (int j = 0; j < 4; ++j) o[j] = (bf16)v[j];
}

// ---------------- hs fp32 -> bf16 ----------------
__global__ __launch_bounds__(256) void cvt_hs(const float* __restrict__ src,
                                              bf16* __restrict__ dst, int n4) {
  const int i = blockIdx.x * 256 + threadIdx.x;
  if (i >= n4) return;
  const float4 f = ((const float4*)src)[i];
  bf16* o = dst + (size_t)i * 4;
  o[0] = (bf16)f.x; o[1] = (bf16)f.y; o[2] = (bf16)f.z; o[3] = (bf16)f.w;
}

// ---------------- depthwise conv + cls concat -> xb bf16 [B][L][768] ----------------
template <int KS>
__global__ __launch_bounds__(256) void conv_kernel(
    const float* __restrict__ hs, const float* __restrict__ cw, bf16* __restrict__ xb) {
  constexpr int OW = 17 - KS;
  constexpr int NOUT = OW * OW;
  constexpr int L = NOUT + 1;
  constexpr int KSQ = KS * KS;
  constexpr int NP = (NOUT + 7) / 8;
  __shared__ float hsl[256][36];
  __shared__ float wsm[32][KSQ];

  const int t = threadIdx.x;
  const int b = blockIdx.y;
  const int c0 = blockIdx.x * 32;

  const float* src = hs + ((size_t)b * SEQ + 1 + t) * DIM + c0;
#pragma unroll
  for (int j = 0; j < 8; ++j) *(float4*)&hsl[t][4 * j] = ((const float4*)src)[j];

  if (t < 32) {
#pragma unroll
    for (int q = 0; q < KSQ; ++q) wsm[t][q] = cw[(size_t)(c0 + t) * KSQ + q];
    const float cv = hs[(size_t)b * SEQ * DIM + c0 + t];
    xb[(size_t)b * L * DIM + c0 + t] = (bf16)cv;
  }
  __syncthreads();

  const int c = t & 31, pg = t >> 5;
#pragma unroll
  for (int i = 0; i < NP; ++i) {
    const int p = pg * NP + i;
    if (p < NOUT) {
      const int oi = p / OW, oj = p - oi * OW;
      float a = 0.f;
#pragma unroll
      for (int di = 0; di < KS; ++di)
#pragma unroll
        for (int dj = 0; dj < KS; ++dj)
          a += hsl[(oi + di) * 16 + oj + dj][c] * wsm[c][di * KS + dj];
      xb[((size_t)b * L + 1 + p) * DIM + c0 + c] = (bf16)a;
    }
  }
}

// ---------------- GEMM core: 128x256 tile, 512 threads (8 waves = 2x4 of 64x64) ----------------
// 3 LDS buffers (72 KB, 2 blocks/CU), counted vmcnt(3), both-sides chunk swizzle,
// STAGE hoisted to iteration top (r24 measured-best).
// OUT: 1 = KV (N=1536: tN<3 K, >=3 V); 3 = fp32 [M][768]; 4 = QKV (N=2304: Q/K/V per 3).
template <int OUT>
__device__ __forceinline__ void gemm_core(
    bf16* sm, const bf16* A, const bf16* W,
    const float* b0, const float* b1, const float* b2,
    void* Y0, void* Y1, void* Y2, int M, int L, int Lv, int tM, int tN, int tid) {
  constexpr int A_E = 128 * 32;  // 4096 elems / buffer
  constexpr int B_E = 256 * 32;  // 8192 elems / buffer
  bf16* smA = sm;                // 3 buffers A
  bf16* smB = sm + 3 * A_E;      // 3 buffers B

  const int lane = tid & 63;
  const int w = tid >> 6;            // 0..7
  const int wrow = (w >> 2) * 64;    // 0,64
  const int wcol = (w & 3) * 64;     // 0,64,128,192
  const int rl = lane & 15;
  const int g = lane >> 4;
  const int kqs = ((g ^ ((rl >> 1) & 3)) << 3);  // read-side chunk deswizzle

  const int sr = lane >> 2;
  const int sk = (((lane & 3) ^ ((sr >> 1) & 3)) << 3);  // staging global pre-swizzle
  long gar = (long)tM * 128 + w * 16 + sr; if (gar >= M) gar = M - 1;
  const bf16* pa  = A + gar * DIM + sk;
  const bf16* pb0 = W + ((size_t)tN * 256 + (2 * w) * 16 + sr) * DIM + sk;
  const bf16* pb1 = W + ((size_t)tN * 256 + (2 * w + 1) * 16 + sr) * DIM + sk;
  const int la  = w * 512;
  const int lb0 = (2 * w) * 512;
  const int lb1 = (2 * w + 1) * 512;

  const f32x4 zero4 = {0.f, 0.f, 0.f, 0.f};
  f32x4 acc[4][4];
#pragma unroll
  for (int m = 0; m < 4; ++m)
#pragma unroll
    for (int n = 0; n < 4; ++n) acc[m][n] = zero4;

  constexpr int NT = DIM / 32;  // 24 K-steps

#define STAGE(kt_, buf_)                                      \
  do {                                                        \
    const int kb_ = (kt_) * 32;                               \
    gload_lds16(pa  + kb_, smA + (buf_) * A_E + la);          \
    gload_lds16(pb0 + kb_, smB + (buf_) * B_E + lb0);         \
    gload_lds16(pb1 + kb_, smB + (buf_) * B_E + lb1);         \
  } while (0)

  STAGE(0, 0);
  STAGE(1, 1);
  asm volatile("s_waitcnt vmcnt(3)" ::: "memory");
  __builtin_amdgcn_s_barrier();
  __builtin_amdgcn_sched_barrier(0);

  int buf = 0;
  for (int kt = 0; kt < NT; ++kt) {
    if (kt + 2 < NT) {
      const int nb = buf + 2 >= 3 ? buf - 1 : buf + 2;
      STAGE(kt + 2, nb);
    }

    const bf16* Ac = smA + buf * A_E;
    const bf16* Bc = smB + buf * B_E;
    bf16x8 af[4], bfr[4];
#pragma unroll
    for (int m = 0; m < 4; ++m) af[m] = *(const bf16x8*)&Ac[(wrow + m * 16 + rl) * 32 + kqs];
#pragma unroll
    for (int n = 0; n < 4; ++n) bfr[n] = *(const bf16x8*)&Bc[(wcol + n * 16 + rl) * 32 + kqs];
#pragma unroll
    for (int m = 0; m < 4; ++m)
#pragma unroll
      for (int n = 0; n < 4; ++n) acc[m][n] = MFMA_BF16(af[m], bfr[n], acc[m][n]);

    if (kt + 1 < NT) {
      if (kt + 2 < NT) asm volatile("s_waitcnt vmcnt(3)" ::: "memory");
      else             asm volatile("s_waitcnt vmcnt(0)" ::: "memory");
      __builtin_amdgcn_s_barrier();
      __builtin_amdgcn_sched_barrier(0);
    }
    buf = buf == 2 ? 0 : buf + 1;
  }
#undef STAGE

  // ---------------- epilogue ----------------
  if constexpr (OUT == 3) {
#pragma unroll
    for (int n = 0; n < 4; ++n) {
      const int gcol = tN * 256 + wcol + n * 16 + rl;
      const float bia = b0[gcol];
#pragma unroll
      for (int m = 0; m < 4; ++m) {
#pragma unroll
        for (int i = 0; i < 4; ++i) {
          const long grow = (long)tM * 128 + wrow + m * 16 + g * 4 + i;
          if (grow < M) ((float*)Y0)[grow * DIM + gcol] = acc[m][n][i] + bia;
        }
      }
    }
    return;
  }

  bf16* smT = sm;
  __syncthreads();  // all compute + DMA done; sm reusable

  const bool qpath = (OUT == 4) && (tN < 3);
  const bool vpath = (OUT == 4) ? (tN >= 6) : (tN >= 3);

  if (vpath) {
    constexpr int TPV = 136;  // row stride pad (col-major store)
    const int cbase = (OUT == 4) ? 1536 : 768;
    const float* bv_ = (OUT == 4) ? b2 : b1;
#pragma unroll
    for (int n = 0; n < 4; ++n) {
      const int col = wcol + n * 16 + rl;
      const float bia = bv_[tN * 256 + col - cbase];
#pragma unroll
      for (int m = 0; m < 4; ++m) {
        const int row = wrow + m * 16 + g * 4;
        bf16x4 v4;
#pragma unroll
        for (int i = 0; i < 4; ++i) v4[i] = (bf16)(acc[m][n][i] + bia);
        *(bf16x4*)(smT + col * TPV + row) = v4;
      }
    }
    __syncthreads();
    bf16* vout = (bf16*)((OUT == 4) ? Y2 : Y1);
    const int tNv = tN - ((OUT == 4) ? 6 : 3);
#pragma unroll
    for (int it = 0; it < 8; ++it) {
      const int c = it * 512 + tid;     // 4096 chunks: 256 cols x 16 row-chunks
      const int coll = c >> 4;
      const int rw0 = (c & 15) * 8;
      const long g2 = (long)tM * 128 + rw0;
      if (g2 < M) {
        const int b2i = (int)(g2 / L);
        const int l2 = (int)(g2 - (long)b2i * L);
        const int cv = tNv * 256 + coll;
        bf16* dst = vout + (((size_t)b2i * NH + (cv >> 6)) * 64 + (cv & 63)) * Lv;
        const bf16x8 v = *(const bf16x8*)(smT + coll * TPV + rw0);
        if (l2 + 8 <= L) {
          *(bf16x8*)(dst + l2) = v;
        } else {
#pragma unroll
          for (int j = 0; j < 8; ++j) {
            const long g3 = g2 + j;
            const int b3 = (int)(g3 / L), l3 = (int)(g3 - (long)b3 * L);
            vout[(((size_t)b3 * NH + (cv >> 6)) * 64 + (cv & 63)) * Lv + l3] = v[j];
          }
        }
      }
    }
  } else {
    constexpr int TPK = 264;  // col stride pad (row-major store)
    const float scale = qpath ? 0.125f : 1.f;
#pragma unroll
    for (int n = 0; n < 4; ++n) {
      const int col = wcol + n * 16 + rl;
      const int gcol = tN * 256 + col;
      float bia;
      if constexpr (OUT == 4) bia = qpath ? b0[gcol] : b1[gcol - 768];
      else                    bia = b0[gcol];
#pragma unroll
      for (int m = 0; m < 4; ++m) {
#pragma unroll
        for (int i = 0; i < 4; ++i) {
          const int row = wrow + m * 16 + g * 4 + i;
          smT[row * TPK + col] = (bf16)((acc[m][n][i] + bia) * scale);
        }
      }
    }
    __syncthreads();
    bf16* kout = (bf16*)(qpath ? Y0 : ((OUT == 4) ? Y1 : Y0));
    const int coff = (OUT == 4 && !qpath) ? 768 : 0;
    const bool kswz = !qpath;  // K outputs chunk-swizzled for attn's linear DMA
#pragma unroll
    for (int it = 0; it < 8; ++it) {
      const int c = it * 512 + tid;     // 4096 chunks: 128 rows x 32 col-chunks
      const int row = c >> 5;
      const int col0 = (c & 31) * 8;
      const long g2 = (long)tM * 128 + row;
      if (g2 < M) {
        const int b2i = (int)(g2 / L);
        const int l2 = (int)(g2 - (long)b2i * L);
        const int gc = tN * 256 + col0 - coff;
        const bf16x8 v = *(const bf16x8*)(smT + row * TPK + col0);
        if (qpath) {
          *(bf16x8*)(kout + (((size_t)b2i * NH + (gc >> 6)) * 257 + l2) * 64 + (gc & 63)) = v;
        } else {
          int dchunk = (gc & 63) >> 3;
          if (kswz) dchunk ^= (l2 & 7);
          *(bf16x8*)(kout + (((size_t)b2i * NH + (gc >> 6)) * L + l2) * 64 + dchunk * 8) = v;
        }
      }
    }
  }
}

__device__ __forceinline__ int m204_swz(int orig, int nwg) {
  const int nq = nwg >> 3, rr = nwg & 7, xcd = orig & 7, base = orig >> 3;
  return (xcd < rr ? xcd * (nq + 1) : rr * (nq + 1) + (xcd - rr) * nq) + base;
}

// ---- QKV0 mega-GEMM: A=hs_bf16, W=[Wq|Wk*c1|Wv*c1], N=2304, nN=9 ----
__global__ __launch_bounds__(512, 4) void gemm_qkv0_kernel(
    const bf16* __restrict__ A, const bf16* __restrict__ W,
    const float* __restrict__ bq, const float* __restrict__ bk, const float* __restrict__ bv,
    bf16* __restrict__ qb, bf16* __restrict__ kb, bf16* __restrict__ vb) {
  __shared__ alignas(16) bf16 sm[36864];
  const int wgid = m204_swz(blockIdx.x, gridDim.x);
  const int tM = wgid / 9, tN = wgid - tM * 9;
  gemm_core<4>(sm, A, W, bq, bk, bv, qb, kb, vb, BATCH * SEQ, 257, 264, tM, tN, threadIdx.x);
}

// ---- fused KV1+KV2 GEMM: [0,594) branch1 (99x6), [594,1032) branch2 (73x6) ----
__global__ __launch_bounds__(512, 4) void gemm_kv12_kernel(
    const bf16* __restrict__ A1, const bf16* __restrict__ A2, const bf16* __restrict__ W,
    const float* __restrict__ bk, const float* __restrict__ bv,
    bf16* __restrict__ k1, bf16* __restrict__ v1,
    bf16* __restrict__ k2, bf16* __restrict__ v2) {
  __shared__ alignas(16) bf16 sm[36864];
  const int wgid = m204_swz(blockIdx.x, gridDim.x);
  if (wgid < 594) {
    const int tM = wgid / 6, tN = wgid - tM * 6;
    gemm_core<1>(sm, A1, W, bk, bv, nullptr, k1, v1, nullptr, BATCH * 197, 197, 200, tM, tN, threadIdx.x);
  } else {
    const int l = wgid - 594;
    const int tM = l / 6, tN = l - tM * 6;
    gemm_core<1>(sm, A2, W, bk, bv, nullptr, k2, v2, nullptr, BATCH * 145, 145, 152, tM, tN, threadIdx.x);
  }
}

// ---- O projection: N=768, nN=3 ----
__global__ __launch_bounds__(512, 4) void gemm_o_kernel(
    const bf16* __restrict__ A, const bf16* __restrict__ W,
    const float* __restrict__ bo, float* __restrict__ out) {
  __shared__ alignas(16) bf16 sm[36864];
  const int wgid = m204_swz(blockIdx.x, gridDim.x);
  const int tM = wgid / 3, tN = wgid - tM * 3;
  gemm_core<3>(sm, A, W, bo, nullptr, nullptr, out, nullptr, nullptr, BATCH * SEQ, 257, 1, tM, tN, threadIdx.x);
}

// ---- cls fixup: branch-0 K/V row l=0 must use UNSCALED Wk/Wv ----
__global__ __launch_bounds__(256) void cls_fixup_kernel(
    const bf16* __restrict__ hsb, const bf16* __restrict__ wk, const bf16* __restrict__ wv,
    const float* __restrict__ bk, const float* __restrict__ bv,
    bf16* __restrict__ k12, bf16* __restrict__ v12) {
  __shared__ float hrow[DIM];
  const int b = blockIdx.y, tile = blockIdx.x, t = threadIdx.x;
  for (int i = t; i < DIM; i += 256) hrow[i] = (float)hsb[(size_t)b * SEQ * DIM + i];
  __syncthreads();
  const bool isv = tile >= 6;
  const int o = (tile - (isv ? 6 : 0)) * 128 + (t >> 1);
  const int half = t & 1;
  const bf16* wrow = (isv ? wv : wk) + (size_t)o * DIM + half * 384;
  float s = 0.f;
#pragma unroll 4
  for (int k = 0; k < 48; ++k) {
    const bf16x8 wv8 = *(const bf16x8*)(wrow + k * 8);
#pragma unroll
    for (int j = 0; j < 8; ++j) s += hrow[half * 384 + k * 8 + j] * (float)wv8[j];
  }
  s += __shfl_xor(s, 1);
  if (!half) {
    s += (isv ? bv : bk)[o];
    if (!isv) {
      k12[(((size_t)b * NH + (o >> 6)) * 257) * 64 + (o & 63)] = (bf16)s;  // l=0: swizzle identity
    } else {
      v12[(((size_t)b * NH + (o >> 6)) * 64 + (o & 63)) * 264] = (bf16)s;
    }
  }
}

// ---------------- fused attention: one block per (b,h), loops over 5 q-tiles ----------------
// (r21/r23/r24-measured structure, no setprio: r25 measured it null-to-negative here)
template <int L, int BRANCH>
__global__ __launch_bounds__(256, 2) void attn_kernel(
    const bf16* __restrict__ qb, const bf16* __restrict__ kb, const bf16* __restrict__ vb,
    float* __restrict__ ctx, bf16* __restrict__ xbuf, int Lv) {
  constexpr int LK16 = (L + 15) & ~15;
  constexpr int NKT = LK16 / 16;
  constexpr int LP32 = (L + 31) & ~31;
  constexpr int NK32 = LP32 / 32;
  constexpr int PSTR = LP32 + 8;
  __shared__ alignas(16) bf16 Ks[LK16 * 64];
  __shared__ alignas(16) bf16 Ps[64 * PSTR];

  const int tid = threadIdx.x, lane = tid & 63, w = tid >> 6;
  const int orig = blockIdx.x;
  const int nper = gridDim.x >> 3;
  const int bh = (orig & 7) * nper + (orig >> 3);
  const int b = bh / NH, h = bh % NH;
  const int cl = lane & 15, g = lane >> 4;

  const bf16* kbase = kb + (size_t)bh * L * 64;
  for (int c = tid; c < LK16 * 8; c += 256)
    gload_lds16(kbase + (size_t)c * 8, Ks + (size_t)c * 8);
  __syncthreads();

  const bf16* vbase = vb + (size_t)bh * 64 * Lv;

  for (int qt = 0; qt < 5; ++qt) {
    int sq = qt * 64 + w * 16 + cl;
    if (sq > 256) sq = 256;
    const bf16* qrow = qb + ((size_t)bh * 257 + sq) * 64 + g * 8;
    const bf16x8 aq0 = *(const bf16x8*)qrow;
    const bf16x8 aq1 = *(const bf16x8*)(qrow + 32);

    float sums[4] = {0.f, 0.f, 0.f, 0.f};
    const int prow0 = (w * 16 + g * 4) * PSTR + cl;
#pragma unroll
    for (int kt = 0; kt < NKT; ++kt) {
      const int key0 = kt * 16 + cl;
      const int sw = key0 & 7;
      const char* krow = (const char*)Ks + key0 * 128;
      const bf16x8 bk0 = *(const bf16x8*)(krow + ((g ^ sw) << 4));
      const bf16x8 bk1 = *(const bf16x8*)(krow + (((4 + g) ^ sw) << 4));
      f32x4 z = {0.f, 0.f, 0.f, 0.f};
      z = MFMA_BF16(aq0, bk0, z);
      z = MFMA_BF16(aq1, bk1, z);
      const bool valid = key0 < L;
#pragma unroll
      for (int j = 0; j < 4; ++j) {
        const float p = valid ? __expf(z[j]) : 0.f;
        sums[j] += p;
        Ps[prow0 + j * PSTR + kt * 16] = (bf16)p;
      }
    }
    if constexpr (LP32 > LK16) {
#pragma unroll
      for (int j = 0; j < 4; ++j) Ps[prow0 + j * PSTR + LK16] = (bf16)0.f;
    }

    bf16x8 vr0[4], vr1[4];
#pragma unroll
    for (int nt = 0; nt < 4; ++nt)
      vr0[nt] = *(const bf16x8*)(vbase + (size_t)(nt * 16 + cl) * Lv + g * 8);

#pragma unroll
    for (int j = 0; j < 4; ++j) {
      sums[j] += __shfl_xor(sums[j], 1);
      sums[j] += __shfl_xor(sums[j], 2);
      sums[j] += __shfl_xor(sums[j], 4);
      sums[j] += __shfl_xor(sums[j], 8);
    }
    float inv[4];
#pragma unroll
    for (int j = 0; j < 4; ++j) inv[j] = 1.f / sums[j];

    f32x4 cacc[4];
#pragma unroll
    for (int nt = 0; nt < 4; ++nt) cacc[nt] = f32x4{0.f, 0.f, 0.f, 0.f};
#pragma unroll
    for (int kt = 0; kt < NK32; ++kt) {
      const bool even = (kt & 1) == 0;
      if (kt + 1 < NK32) {
        int kk = (kt + 1) * 32 + g * 8;
        if (kk > Lv - 8) kk = Lv - 8;
#pragma unroll
        for (int nt = 0; nt < 4; ++nt) {
          const bf16x8 v = *(const bf16x8*)(vbase + (size_t)(nt * 16 + cl) * Lv + kk);
          if (even) vr1[nt] = v; else vr0[nt] = v;
        }
      }
      const bf16x8 ap = *(const bf16x8*)&Ps[(w * 16 + cl) * PSTR + kt * 32 + g * 8];
#pragma unroll
      for (int nt = 0; nt < 4; ++nt)
        cacc[nt] = MFMA_BF16(ap, even ? vr0[nt] : vr1[nt], cacc[nt]);
    }

#pragma unroll
    for (int nt = 0; nt < 4; ++nt) {
#pragma unroll
      for (int i = 0; i < 4; ++i) {
        const int s_q = qt * 64 + w * 16 + g * 4 + i;
        if (s_q < 257) {
          const size_t idx = ((size_t)b * 257 + s_q) * DIM + h * 64 + nt * 16 + cl;
          const float val = cacc[nt][i] * inv[i];
          if constexpr (BRANCH == 0)
            ctx[idx] = val;
          else if constexpr (BRANCH == 1)
            ctx[idx] += val;
          else
            xbuf[idx] = (bf16)((ctx[idx] + val) * (1.f / 3.f));
        }
      }
    }
  }
}

extern "C" void kernel_launch(void* const* d_in, const int* in_sizes, int n_in,
                              void* d_out, int out_size, void* d_ws, size_t ws_size,
                              hipStream_t stream) {
  (void)in_sizes; (void)n_in; (void)out_size; (void)ws_size;
  const float* hs = (const float*)d_in[0];
  const float* Wq = (const float*)d_in[1];
  const float* bq = (const float*)d_in[2];
  const float* Wk = (const float*)d_in[3];
  const float* bk = (const float*)d_in[4];
  const float* Wv = (const float*)d_in[5];
  const float* bv = (const float*)d_in[6];
  const float* Wo = (const float*)d_in[7];
  const float* bo = (const float*)d_in[8];
  const float* c1 = (const float*)d_in[9];
  const float* c2 = (const float*)d_in[10];
  const float* c3 = (const float*)d_in[11];
  float* out = (float*)d_out;

  constexpr size_t QB = (size_t)BATCH * NH * SEQ * 64;
  constexpr size_t XB = (size_t)BATCH * SEQ * DIM;
  constexpr size_t K12 = (size_t)BATCH * NH * 257 * 64;
  constexpr size_t V12 = (size_t)BATCH * NH * 64 * 264;
  constexpr size_t XB3 = (size_t)BATCH * 145 * DIM;
  constexpr size_t K3 = (size_t)BATCH * NH * 145 * 64;

  bf16* wbf = (bf16*)d_ws;           // [Wq|Wk*c1|Wv*c1|Wk|Wv|Wo] 6*WE
  bf16* qb  = wbf + 6 * WE;
  bf16* xb  = qb + QB;               // hsb, later conv2 output; finally ctx/3 bf16
  bf16* k12 = xb + XB;               // branch0 K, later branch1 K
  bf16* v12 = k12 + K12;             // branch0 V, later branch1 V
  bf16* xb3 = v12 + V12;             // conv3 output
  bf16* k3  = xb3 + XB3;
  bf16* v3  = k3 + K3;
  bf16* hsb = xb;

  cvt_weights6<<<dim3((unsigned)((6 * WE / 4 + 255) / 256)), 256, 0, stream>>>(Wq, Wk, Wv, Wo, c1, wbf);
  cvt_hs<<<dim3((BATCH * SEQ * DIM / 4 + 255) / 256), 256, 0, stream>>>(hs, hsb, BATCH * SEQ * DIM / 4);

  // ---- branch 0 (1x1 conv folded into weights): Q, K0, V0 in one GEMM + cls fixup ----
  gemm_qkv0_kernel<<<dim3(129 * 9), 512, 0, stream>>>(hsb, wbf, bq, bk, bv, qb, k12, v12);
  cls_fixup_kernel<<<dim3(12, 64), 256, 0, stream>>>(hsb, wbf + 3 * WE, wbf + 4 * WE, bk, bv, k12, v12);
  attn_kernel<257, 0><<<dim3(768), 256, 0, stream>>>(qb, k12, v12, out, xb, 264);

  // ---- branches 1 & 2: convs, fused KV GEMM, attns ----
  conv_kernel<3><<<dim3(24, 64), 256, 0, stream>>>(hs, c2, xb);
  conv_kernel<5><<<dim3(24, 64), 256, 0, stream>>>(hs, c3, xb3);
  gemm_kv12_kernel<<<dim3(594 + 438), 512, 0, stream>>>(xb, xb3, wbf + 3 * WE, bk, bv,
                                                        k12, v12, k3, v3);
  attn_kernel<197, 1><<<dim3(768), 256, 0, stream>>>(qb, k12, v12, out, xb, 200);
  attn_kernel<145, 2><<<dim3(768), 256, 0, stream>>>(qb, k3, v3, out, xb, 152);

  // ---- output projection ----
  gemm_o_kernel<<<dim3(129 * 3), 512, 0, stream>>>(xb, wbf + 5 * WE, bo, out);
}